// Round 5
// baseline (490.488 us; speedup 1.0000x reference)
//
#include <hip/hip_runtime.h>
#include <math.h>

// Sparse EdgeConvE round 5: occupancy + latency attack.
//   h1 = relu( U[i] + V[j] + e_ij @ We ),  U = x@(Wxi-Wxj)+ba, V = x@Wxj
//   out[i] += relu( h1 @ Wb + bb )   (per-edge relu, then sum over j)
// conv_kernel: persistent waves, 16 edges/wave in 4-edge ILP groups,
// Wb staged in LDS per block (no 64-reg array), next-group loads prefetched
// into registers, run-length atomic flush on i (edge list is i-grouped).

#define NN 768
#define FF 64
#define DE 32
#define HH 64
#define NBLK 512
#define WPB 4
#define NWAVES (NBLK * WPB)
#define EPG 4               // edges per ILP group
#define GPC 4               // groups per chunk
#define CPW (EPG * GPC)     // 16 edges per wave-chunk

__global__ __launch_bounds__(256) void scan_kernel(
    const float* __restrict__ A, int* __restrict__ gcnt, int* __restrict__ edges)
{
  const int i = blockIdx.x;
  const int tid = threadIdx.x;
  __shared__ int s_cnt, s_base;
  __shared__ int s_j[NN];
  if (tid == 0) s_cnt = 0;
  __syncthreads();
  for (int j = tid; j < NN; j += 256) {
    if (A[i * NN + j] != 0.0f) {
      int p = atomicAdd(&s_cnt, 1);
      s_j[p] = j;
    }
  }
  __syncthreads();
  if (tid == 0) s_base = atomicAdd(gcnt, s_cnt);
  __syncthreads();
  const int c = s_cnt, b = s_base;
  for (int t = tid; t < c; t += 256) edges[b + t] = (i << 10) | s_j[t];
}

// U[r][c] = sum_d x[r][d]*(W[d][c]-W[64+d][c]) + bias[c];  V[r][c] = sum_d x[r][d]*W[64+d][c]
__global__ __launch_bounds__(256, 4) void uv_kernel(
    const float* __restrict__ x, const float* __restrict__ W,
    const float* __restrict__ bias, float* __restrict__ U, float* __restrict__ V)
{
  const int tid = threadIdx.x;
  const int rr = tid >> 6, c = tid & 63;
  const int r = blockIdx.x * 4 + rr;
  __shared__ float sx[4][64];
  sx[rr][c] = x[r * 64 + c];
  __syncthreads();
  float u = bias[c], v = 0.0f;
#pragma unroll
  for (int d = 0; d < 64; ++d) {
    float xv = sx[rr][d];
    float wxi = W[d * 64 + c];
    float wxj = W[(64 + d) * 64 + c];
    u = fmaf(xv, wxi - wxj, u);
    v = fmaf(xv, wxj, v);
  }
  U[r * 64 + c] = u;
  V[r * 64 + c] = v;
}

__global__ __launch_bounds__(256, 4) void conv_kernel(
    const int* __restrict__ gcnt, const int* __restrict__ edges,
    const float* __restrict__ U, const float* __restrict__ V,
    const float* __restrict__ e, const float* __restrict__ We,   // [32][64]
    const float* __restrict__ Wb, const float* __restrict__ bb,  // [64][64]
    float* __restrict__ xout)
{
  const int tid = threadIdx.x, lane = tid & 63, wv = tid >> 6;

  __shared__ __align__(16) float sWb[HH * HH];            // 16 KB
  __shared__ __align__(16) float se[WPB][2][EPG][DE];     // 4 KB
  __shared__ __align__(16) float sh1[WPB][2][EPG * HH];   // 8 KB

  // stage Wb once per block
  for (int idx = tid; idx < HH * HH / 4; idx += 256)
    ((float4*)sWb)[idx] = ((const float4*)Wb)[idx];
  __syncthreads();   // only block-wide barrier; hot loop below is wave-local

  const int M = gcnt[0];
  float w1e[DE];
#pragma unroll
  for (int d = 0; d < DE; ++d) w1e[d] = We[d * HH + lane];
  const float bias2 = bb[lane];

  const int wgid = blockIdx.x * WPB + wv;
  const int et = lane >> 4;            // staging edge slot 0..3
  const int ed = (lane & 15) * 2;      // staging dim pair

  for (int c0 = wgid * CPW; c0 < M; c0 += NWAVES * CPW) {
    // chunk edge descriptors (uniform, clamped so OOB slots read valid memory)
    int pm[CPW];
    bool val[CPW];
#pragma unroll
    for (int t = 0; t < CPW; ++t) {
      int m = c0 + t;
      val[t] = m < M;
      pm[t] = edges[val[t] ? m : M - 1];
    }
    float acc = 0.0f;
    int cur_i = pm[0] >> 10;

    float uu[2][EPG], vv[2][EPG];
    float2 e2[2];
    // prefetch group 0 (loads only; adds deferred to use site)
#pragma unroll
    for (int t = 0; t < EPG; ++t) {
      int p = pm[t];
      uu[0][t] = U[((p >> 10) << 6) + lane];
      vv[0][t] = V[((p & 1023) << 6) + lane];
    }
    {
      int p = pm[et];
      e2[0] = *(const float2*)(e + (size_t)((p >> 10) * NN + (p & 1023)) * DE + ed);
    }

#pragma unroll
    for (int g = 0; g < GPC; ++g) {
      const int cur = g & 1, nxt = cur ^ 1;
      // issue next group's loads before touching current data
      if (g + 1 < GPC) {
#pragma unroll
        for (int t = 0; t < EPG; ++t) {
          int p = pm[(g + 1) * EPG + t];
          uu[nxt][t] = U[((p >> 10) << 6) + lane];
          vv[nxt][t] = V[((p & 1023) << 6) + lane];
        }
        int p = pm[(g + 1) * EPG + et];
        e2[nxt] = *(const float2*)(e + (size_t)((p >> 10) * NN + (p & 1023)) * DE + ed);
      }

      // stage current group's e rows (double-buffered per wave)
      *(float2*)&se[wv][cur][et][ed] = e2[cur];
      __builtin_amdgcn_wave_barrier();

      // ---- layer 1: 4 edges ----
#pragma unroll
      for (int t = 0; t < EPG; ++t) {
        float h = uu[cur][t] + vv[cur][t];
        const float4* fe = (const float4*)se[wv][cur][t];
#pragma unroll
        for (int dq = 0; dq < 8; ++dq) {
          float4 f = fe[dq];           // uniform LDS broadcast
          h = fmaf(f.x, w1e[4 * dq + 0], h);
          h = fmaf(f.y, w1e[4 * dq + 1], h);
          h = fmaf(f.z, w1e[4 * dq + 2], h);
          h = fmaf(f.w, w1e[4 * dq + 3], h);
        }
        sh1[wv][cur][t * HH + lane] = fmaxf(h, 0.0f);   // 2-way bank alias: free
      }
      __builtin_amdgcn_wave_barrier();

      // ---- layer 2: 4 edges share each Wb column read ----
      float q[EPG] = {bias2, bias2, bias2, bias2};
#pragma unroll
      for (int cq = 0; cq < 16; ++cq) {
        float wb0 = sWb[(4 * cq + 0) * HH + lane];
        float wb1 = sWb[(4 * cq + 1) * HH + lane];
        float wb2 = sWb[(4 * cq + 2) * HH + lane];
        float wb3 = sWb[(4 * cq + 3) * HH + lane];
#pragma unroll
        for (int t = 0; t < EPG; ++t) {
          float4 hq = ((const float4*)&sh1[wv][cur][t * HH])[cq];  // uniform
          q[t] = fmaf(hq.x, wb0, q[t]);
          q[t] = fmaf(hq.y, wb1, q[t]);
          q[t] = fmaf(hq.z, wb2, q[t]);
          q[t] = fmaf(hq.w, wb3, q[t]);
        }
      }

      // ---- accumulate with run-length flush on i (uniform branches) ----
#pragma unroll
      for (int t = 0; t < EPG; ++t) {
        const int gt = g * EPG + t;
        if (val[gt]) {
          const int it = pm[gt] >> 10;
          if (it != cur_i) {
            atomicAdd(&xout[(cur_i << 6) + lane], acc);
            acc = 0.0f;
            cur_i = it;
          }
          acc += fmaxf(q[t], 0.0f);
        }
      }
      __builtin_amdgcn_wave_barrier();  // keep next group's se/sh1 writes ordered
    }
    atomicAdd(&xout[(cur_i << 6) + lane], acc);
  }
}

// x2[768,64] -> relu(x2 @ W3[64,128] + b3) -> sigmoid(@ W4[128,1] + b4)
__global__ __launch_bounds__(128) void final_kernel(
    const float* __restrict__ x2, const float* __restrict__ W3,
    const float* __restrict__ b3, const float* __restrict__ W4,
    const float* __restrict__ b4, float* __restrict__ out)
{
  const int i = blockIdx.x;
  const int t = threadIdx.x;
  const int lane = t & 63;
  const int wv = t >> 6;
  __shared__ float sx[64];
  __shared__ float s_red[2];
  if (t < 64) sx[t] = x2[i * 64 + t];
  __syncthreads();
  float p = b3[t];
#pragma unroll
  for (int c = 0; c < 64; ++c) p = fmaf(sx[c], W3[c * 128 + t], p);
  p = fmaxf(p, 0.0f);
  float v = p * W4[t];
  v += __shfl_down(v, 32);
  v += __shfl_down(v, 16);
  v += __shfl_down(v, 8);
  v += __shfl_down(v, 4);
  v += __shfl_down(v, 2);
  v += __shfl_down(v, 1);
  if (lane == 0) s_red[wv] = v;
  __syncthreads();
  if (t == 0) {
    float z = s_red[0] + s_red[1] + b4[0];
    out[i] = 1.0f / (1.0f + expf(-z));
  }
}

extern "C" void kernel_launch(void* const* d_in, const int* in_sizes, int n_in,
                              void* d_out, int out_size, void* d_ws, size_t ws_size,
                              hipStream_t stream) {
  const float* A   = (const float*)d_in[0];
  const float* x   = (const float*)d_in[1];
  const float* e   = (const float*)d_in[2];
  const float* W1a = (const float*)d_in[3];
  const float* b1a = (const float*)d_in[4];
  const float* W1b = (const float*)d_in[5];
  const float* b1b = (const float*)d_in[6];
  const float* W2a = (const float*)d_in[7];
  const float* b2a = (const float*)d_in[8];
  const float* W2b = (const float*)d_in[9];
  const float* b2b = (const float*)d_in[10];
  const float* W3  = (const float*)d_in[11];
  const float* b3  = (const float*)d_in[12];
  const float* W4  = (const float*)d_in[13];
  const float* b4  = (const float*)d_in[14];
  float* out = (float*)d_out;

  // ws layout: [gcnt(16 ints) | x1 | x2 | U1 | V1 | U2 | V2 | edges]
  int*   gcnt  = (int*)d_ws;
  float* x1    = (float*)d_ws + 16;
  float* x2    = x1 + NN * HH;
  float* U1    = x2 + NN * HH;
  float* V1    = U1 + NN * HH;
  float* U2    = V1 + NN * HH;
  float* V2    = U2 + NN * HH;
  int*   edges = (int*)(V2 + NN * HH);

  hipMemsetAsync(d_ws, 0, (16 + 2 * NN * HH) * sizeof(float), stream);

  scan_kernel<<<NN, 256, 0, stream>>>(A, gcnt, edges);
  uv_kernel<<<NN / 4, 256, 0, stream>>>(x, W1a, b1a, U1, V1);
  conv_kernel<<<NBLK, 256, 0, stream>>>(gcnt, edges, U1, V1, e, W1a + 128 * HH,
                                        W1b, b1b, x1);
  uv_kernel<<<NN / 4, 256, 0, stream>>>(x1, W2a, b2a, U2, V2);
  conv_kernel<<<NBLK, 256, 0, stream>>>(gcnt, edges, U2, V2, e, W2a + 128 * HH,
                                        W2b, b2b, x2);
  final_kernel<<<NN, 128, 0, stream>>>(x2, W3, b3, W4, b4, out);
}

// Round 6
// 183.949 us; speedup vs baseline: 2.6664x; 2.6664x over previous
//
#include <hip/hip_runtime.h>
#include <math.h>

// Sparse EdgeConvE round 6: flat-edge blocks, small register footprint.
//   h1 = relu( U[i] + V[j] + e_ij @ We ),  U = x@(Wxi-Wdelta)+ba, V = x@Wdelta
//   out[i] = sum_j relu( h1 @ Wb + bb )
// conv_kernel: block = 32 consecutive edges. Phase A: 8 edges/wave,
// lane=channel, full unroll (8 independent load chains, no spill-prone
// arrays). Phase B: channel-split (w2[16]/lane), shfl reduce, run-length
// atomic flush on i (edge list is i-contiguous per row).

#define NN 768
#define FF 64
#define DE 32
#define HH 64
#define EPB 32              // edges per conv block
#define CGRID 1024          // covers M <= 32768 (measured M ~29.5k)

__global__ __launch_bounds__(256) void scan_kernel(
    const float* __restrict__ A, int* __restrict__ gcnt, int* __restrict__ edges)
{
  const int i = blockIdx.x;
  const int tid = threadIdx.x;
  __shared__ int s_cnt, s_base;
  __shared__ int s_j[NN];
  if (tid == 0) s_cnt = 0;
  __syncthreads();
  for (int j = tid; j < NN; j += 256) {
    if (A[i * NN + j] != 0.0f) {
      int p = atomicAdd(&s_cnt, 1);
      s_j[p] = j;
    }
  }
  __syncthreads();
  if (tid == 0) s_base = atomicAdd(gcnt, s_cnt);
  __syncthreads();
  const int c = s_cnt, b = s_base;
  for (int t = tid; t < c; t += 256) edges[b + t] = (i << 10) | s_j[t];
}

// U[r][c] = sum_d x[r][d]*(W[d][c]-W[64+d][c]) + bias[c];  V[r][c] = sum_d x[r][d]*W[64+d][c]
__global__ __launch_bounds__(256, 4) void uv_kernel(
    const float* __restrict__ x, const float* __restrict__ W,
    const float* __restrict__ bias, float* __restrict__ U, float* __restrict__ V)
{
  const int tid = threadIdx.x;
  const int rr = tid >> 6, c = tid & 63;
  const int r = blockIdx.x * 4 + rr;
  __shared__ float sx[4][64];
  sx[rr][c] = x[r * 64 + c];
  __syncthreads();
  float u = bias[c], v = 0.0f;
#pragma unroll
  for (int d = 0; d < 64; ++d) {
    float xv = sx[rr][d];
    float wxi = W[d * 64 + c];
    float wxj = W[(64 + d) * 64 + c];
    u = fmaf(xv, wxi - wxj, u);
    v = fmaf(xv, wxj, v);
  }
  U[r * 64 + c] = u;
  V[r * 64 + c] = v;
}

__global__ void conv_kernel(
    const int* __restrict__ gcnt, const int* __restrict__ edges,
    const float* __restrict__ U, const float* __restrict__ V,
    const float* __restrict__ e, const float* __restrict__ We,   // [32][64]
    const float* __restrict__ Wb, const float* __restrict__ bb,  // [64][64]
    float* __restrict__ xout)
{
  const int tid = threadIdx.x, lane = tid & 63, wv = tid >> 6;
  const int M = gcnt[0];
  const int base = blockIdx.x * EPB;
  if (base >= M) return;
  const int nedge = min(EPB, M - base);

  __shared__ __align__(16) float sh1[EPB * HH];  // 8 KB

  // ---- phase A: 8 edges per wave, lane = output channel ----
  float w1e[DE];
#pragma unroll
  for (int d = 0; d < DE; ++d) w1e[d] = We[d * HH + lane];

  const int a0 = wv * 8;
#pragma unroll
  for (int t = 0; t < 8; ++t) {
    int m = base + a0 + t;
    m = m < M ? m : M - 1;               // clamp: pad edges compute garbage,
    const int p = edges[m];              // phase B never reads those slots
    const int i = p >> 10, j = p & 1023;
    float h = U[(i << 6) + lane] + V[(j << 6) + lane];
    const float4* ep = (const float4*)(e + ((size_t)i * NN + j) * DE);
#pragma unroll
    for (int u = 0; u < 8; ++u) {
      float4 f = ep[u];                  // uniform address -> broadcast
      h = fmaf(f.x, w1e[4 * u + 0], h);
      h = fmaf(f.y, w1e[4 * u + 1], h);
      h = fmaf(f.z, w1e[4 * u + 2], h);
      h = fmaf(f.w, w1e[4 * u + 3], h);
    }
    sh1[(a0 + t) * HH + lane] = fmaxf(h, 0.0f);
  }

  // ---- phase B weights (load early to overlap) ----
  const int slice = lane >> 4, kk = lane & 15;
  const int k = wv * 16 + kk;
  float w2[16];
#pragma unroll
  for (int t = 0; t < 16; ++t) w2[t] = Wb[(slice * 16 + t) * HH + k];
  const float bias2 = bb[k];

  __syncthreads();

  // ---- phase B: all 32 edges, channel-split, run-length flush on i ----
  float acc = 0.0f;
  int cur_i = -1;
  for (int t = 0; t < nedge; ++t) {
    const int p = edges[base + t];       // uniform, L1-hot
    const int i = p >> 10;
    const float4* hp = (const float4*)(sh1 + t * HH + slice * 16);
    float q = bias2;
#pragma unroll
    for (int u = 0; u < 4; ++u) {
      float4 h = hp[u];
      q = fmaf(h.x, w2[4 * u + 0], q);
      q = fmaf(h.y, w2[4 * u + 1], q);
      q = fmaf(h.z, w2[4 * u + 2], q);
      q = fmaf(h.w, w2[4 * u + 3], q);
    }
    q += __shfl_down(q, 32);
    q += __shfl_down(q, 16);
    const float h2 = fmaxf(q, 0.0f);     // valid in lanes 0..15
    if (i != cur_i) {
      if (cur_i >= 0 && lane < 16) atomicAdd(&xout[(cur_i << 6) + k], acc);
      acc = 0.0f;
      cur_i = i;
    }
    acc += h2;
  }
  if (cur_i >= 0 && lane < 16) atomicAdd(&xout[(cur_i << 6) + k], acc);
}

// x2[768,64] -> relu(x2 @ W3[64,128] + b3) -> sigmoid(@ W4[128,1] + b4)
__global__ __launch_bounds__(128) void final_kernel(
    const float* __restrict__ x2, const float* __restrict__ W3,
    const float* __restrict__ b3, const float* __restrict__ W4,
    const float* __restrict__ b4, float* __restrict__ out)
{
  const int i = blockIdx.x;
  const int t = threadIdx.x;
  const int lane = t & 63;
  const int wv = t >> 6;
  __shared__ float sx[64];
  __shared__ float s_red[2];
  if (t < 64) sx[t] = x2[i * 64 + t];
  __syncthreads();
  float p = b3[t];
#pragma unroll
  for (int c = 0; c < 64; ++c) p = fmaf(sx[c], W3[c * 128 + t], p);
  p = fmaxf(p, 0.0f);
  float v = p * W4[t];
  v += __shfl_down(v, 32);
  v += __shfl_down(v, 16);
  v += __shfl_down(v, 8);
  v += __shfl_down(v, 4);
  v += __shfl_down(v, 2);
  v += __shfl_down(v, 1);
  if (lane == 0) s_red[wv] = v;
  __syncthreads();
  if (t == 0) {
    float z = s_red[0] + s_red[1] + b4[0];
    out[i] = 1.0f / (1.0f + expf(-z));
  }
}

extern "C" void kernel_launch(void* const* d_in, const int* in_sizes, int n_in,
                              void* d_out, int out_size, void* d_ws, size_t ws_size,
                              hipStream_t stream) {
  const float* A   = (const float*)d_in[0];
  const float* x   = (const float*)d_in[1];
  const float* e   = (const float*)d_in[2];
  const float* W1a = (const float*)d_in[3];
  const float* b1a = (const float*)d_in[4];
  const float* W1b = (const float*)d_in[5];
  const float* b1b = (const float*)d_in[6];
  const float* W2a = (const float*)d_in[7];
  const float* b2a = (const float*)d_in[8];
  const float* W2b = (const float*)d_in[9];
  const float* b2b = (const float*)d_in[10];
  const float* W3  = (const float*)d_in[11];
  const float* b3  = (const float*)d_in[12];
  const float* W4  = (const float*)d_in[13];
  const float* b4  = (const float*)d_in[14];
  float* out = (float*)d_out;

  // ws layout: [gcnt(16 ints) | x1 | x2 | U1 | V1 | U2 | V2 | edges]
  int*   gcnt  = (int*)d_ws;
  float* x1    = (float*)d_ws + 16;
  float* x2    = x1 + NN * HH;
  float* U1    = x2 + NN * HH;
  float* V1    = U1 + NN * HH;
  float* U2    = V1 + NN * HH;
  float* V2    = U2 + NN * HH;
  int*   edges = (int*)(V2 + NN * HH);

  hipMemsetAsync(d_ws, 0, (16 + 2 * NN * HH) * sizeof(float), stream);

  scan_kernel<<<NN, 256, 0, stream>>>(A, gcnt, edges);
  uv_kernel<<<NN / 4, 256, 0, stream>>>(x, W1a, b1a, U1, V1);
  conv_kernel<<<CGRID, 256, 0, stream>>>(gcnt, edges, U1, V1, e, W1a + 128 * HH,
                                         W1b, b1b, x1);
  uv_kernel<<<NN / 4, 256, 0, stream>>>(x1, W2a, b2a, U2, V2);
  conv_kernel<<<CGRID, 256, 0, stream>>>(gcnt, edges, U2, V2, e, W2a + 128 * HH,
                                         W2b, b2b, x2);
  final_kernel<<<NN, 128, 0, stream>>>(x2, W3, b3, W4, b4, out);
}

// Round 7
// 181.335 us; speedup vs baseline: 2.7049x; 1.0144x over previous
//
#include <hip/hip_runtime.h>
#include <math.h>

// Sparse EdgeConvE round 7:
//   h1 = relu( U[i] + V[j] + e_ij @ We ),  U = x@(Wxi-Wxj)+ba, V = x@Wxj
//   out[i] = sum_j relu( h1 @ Wb + bb )
// Key changes vs r6:
//  - conv1 also computes ew2[m] = e_ij @ We2 while e is in registers; conv2
//    reads ew2 sequentially (no random e gather in layer 2).
//  - scan + UV1 + x1/x2 zeroing fused into one kernel (6 dispatches total).
//  - phase B edge ids come from LDS (si), not global re-reads.

#define NN 768
#define FF 64
#define DE 32
#define HH 64
#define EPB 32              // edges per conv block
#define CGRID 1024          // covers M <= 32768 (measured M ~29.5k)
#define ECAP (NN * 128)     // flat edge-list capacity

// row scan -> flat edge list; U1/V1 for the row; zero x1/x2 rows
__global__ __launch_bounds__(256) void scan_uv_kernel(
    const float* __restrict__ A, const float* __restrict__ x,
    const float* __restrict__ W, const float* __restrict__ bias,
    int* __restrict__ gcnt, int* __restrict__ edges,
    float* __restrict__ U, float* __restrict__ V,
    float* __restrict__ x1, float* __restrict__ x2)
{
  const int i = blockIdx.x;
  const int tid = threadIdx.x;
  __shared__ int s_cnt, s_base;
  __shared__ int s_j[NN];
  __shared__ float sx[64];
  __shared__ float su[4][64], sv[4][64];

  if (tid == 0) s_cnt = 0;
  __syncthreads();
  if (tid < 64) sx[tid] = x[i * 64 + tid];
  for (int j = tid; j < NN; j += 256) {
    if (A[i * NN + j] != 0.0f) {
      int p = atomicAdd(&s_cnt, 1);
      s_j[p] = j;
    }
  }
  if (tid < 64) { x1[i * 64 + tid] = 0.0f; x2[i * 64 + tid] = 0.0f; }
  __syncthreads();

  // U/V partials: c = tid&63, K-quarter = tid>>6
  {
    const int c = tid & 63, qr = tid >> 6;
    float u = 0.0f, v = 0.0f;
#pragma unroll
    for (int t = 0; t < 16; ++t) {
      const int d = qr * 16 + t;
      const float xv = sx[d];
      const float wxi = W[d * 64 + c];
      const float wxj = W[(64 + d) * 64 + c];
      u = fmaf(xv, wxi - wxj, u);
      v = fmaf(xv, wxj, v);
    }
    su[qr][c] = u; sv[qr][c] = v;
  }
  if (tid == 0) s_base = atomicAdd(gcnt, s_cnt);
  __syncthreads();

  if (tid < 64) {
    U[i * 64 + tid] = su[0][tid] + su[1][tid] + su[2][tid] + su[3][tid] + bias[tid];
    V[i * 64 + tid] = sv[0][tid] + sv[1][tid] + sv[2][tid] + sv[3][tid];
  }
  const int c = s_cnt, b = s_base;
  for (int t = tid; t < c; t += 256) edges[b + t] = (i << 10) | s_j[t];
}

// U2[r][c] from x1 (needs conv1 output) — same as r6 uv
__global__ __launch_bounds__(256, 4) void uv_kernel(
    const float* __restrict__ x, const float* __restrict__ W,
    const float* __restrict__ bias, float* __restrict__ U, float* __restrict__ V)
{
  const int tid = threadIdx.x;
  const int rr = tid >> 6, c = tid & 63;
  const int r = blockIdx.x * 4 + rr;
  __shared__ float sx[4][64];
  sx[rr][c] = x[r * 64 + c];
  __syncthreads();
  float u = bias[c], v = 0.0f;
#pragma unroll
  for (int d = 0; d < 64; ++d) {
    float xv = sx[rr][d];
    float wxi = W[d * 64 + c];
    float wxj = W[(64 + d) * 64 + c];
    u = fmaf(xv, wxi - wxj, u);
    v = fmaf(xv, wxj, v);
  }
  U[r * 64 + c] = u;
  V[r * 64 + c] = v;
}

// conv layer 1 + side-product ew2[m] = e_ij @ We2
__global__ void conv1_kernel(
    const int* __restrict__ gcnt, const int* __restrict__ edges,
    const float* __restrict__ U, const float* __restrict__ V,
    const float* __restrict__ e, const float* __restrict__ We1,
    const float* __restrict__ We2, const float* __restrict__ Wb,
    const float* __restrict__ bb, float* __restrict__ xout,
    float* __restrict__ ew2)
{
  const int tid = threadIdx.x, lane = tid & 63, wv = tid >> 6;
  const int M = gcnt[0];
  const int base = blockIdx.x * EPB;
  if (base >= M) return;
  const int nedge = min(EPB, M - base);

  __shared__ __align__(16) float sh1[EPB * HH];  // 8 KB
  __shared__ int si[EPB];

  float w1e[DE], w2e[DE];
#pragma unroll
  for (int d = 0; d < DE; ++d) { w1e[d] = We1[d * HH + lane]; w2e[d] = We2[d * HH + lane]; }

  const int a0 = wv * 8;
#pragma unroll
  for (int t = 0; t < 8; ++t) {
    int m = base + a0 + t;
    const bool valid = m < M;
    m = valid ? m : M - 1;
    const int p = edges[m];
    const int i = p >> 10, j = p & 1023;
    float h = U[(i << 6) + lane] + V[(j << 6) + lane];
    float g = 0.0f;
    const float4* ep = (const float4*)(e + ((size_t)i * NN + j) * DE);
#pragma unroll
    for (int u = 0; u < 8; ++u) {
      float4 f = ep[u];                  // uniform address -> broadcast
      h = fmaf(f.x, w1e[4 * u + 0], h);
      h = fmaf(f.y, w1e[4 * u + 1], h);
      h = fmaf(f.z, w1e[4 * u + 2], h);
      h = fmaf(f.w, w1e[4 * u + 3], h);
      g = fmaf(f.x, w2e[4 * u + 0], g);
      g = fmaf(f.y, w2e[4 * u + 1], g);
      g = fmaf(f.z, w2e[4 * u + 2], g);
      g = fmaf(f.w, w2e[4 * u + 3], g);
    }
    sh1[(a0 + t) * HH + lane] = fmaxf(h, 0.0f);
    if (valid) ew2[(size_t)m * HH + lane] = g;   // streaming, coalesced
    if (lane == 0) si[a0 + t] = i;
  }

  // phase B weights
  const int slice = lane >> 4, kk = lane & 15;
  const int k = wv * 16 + kk;
  float w2[16];
#pragma unroll
  for (int t = 0; t < 16; ++t) w2[t] = Wb[(slice * 16 + t) * HH + k];
  const float bias2 = bb[k];

  __syncthreads();

  float acc = 0.0f;
  int cur_i = -1;
  for (int t = 0; t < nedge; ++t) {
    const int i = si[t];
    const float4* hp = (const float4*)(sh1 + t * HH + slice * 16);
    float q = bias2;
#pragma unroll
    for (int u = 0; u < 4; ++u) {
      float4 h = hp[u];
      q = fmaf(h.x, w2[4 * u + 0], q);
      q = fmaf(h.y, w2[4 * u + 1], q);
      q = fmaf(h.z, w2[4 * u + 2], q);
      q = fmaf(h.w, w2[4 * u + 3], q);
    }
    q += __shfl_down(q, 32);
    q += __shfl_down(q, 16);
    const float h2 = fmaxf(q, 0.0f);
    if (i != cur_i) {
      if (cur_i >= 0 && lane < 16) atomicAdd(&xout[(cur_i << 6) + k], acc);
      acc = 0.0f;
      cur_i = i;
    }
    acc += h2;
  }
  if (cur_i >= 0 && lane < 16) atomicAdd(&xout[(cur_i << 6) + k], acc);
}

// conv layer 2: e-contribution comes precomputed (sequential ew2 rows)
__global__ void conv2_kernel(
    const int* __restrict__ gcnt, const int* __restrict__ edges,
    const float* __restrict__ U, const float* __restrict__ V,
    const float* __restrict__ ew2, const float* __restrict__ Wb,
    const float* __restrict__ bb, float* __restrict__ xout)
{
  const int tid = threadIdx.x, lane = tid & 63, wv = tid >> 6;
  const int M = gcnt[0];
  const int base = blockIdx.x * EPB;
  if (base >= M) return;
  const int nedge = min(EPB, M - base);

  __shared__ __align__(16) float sh1[EPB * HH];
  __shared__ int si[EPB];

  const int a0 = wv * 8;
#pragma unroll
  for (int t = 0; t < 8; ++t) {
    int m = base + a0 + t;
    m = m < M ? m : M - 1;
    const int p = edges[m];
    const int i = p >> 10, j = p & 1023;
    const float h = U[(i << 6) + lane] + V[(j << 6) + lane]
                  + ew2[(size_t)m * HH + lane];
    sh1[(a0 + t) * HH + lane] = fmaxf(h, 0.0f);
    if (lane == 0) si[a0 + t] = i;
  }

  const int slice = lane >> 4, kk = lane & 15;
  const int k = wv * 16 + kk;
  float w2[16];
#pragma unroll
  for (int t = 0; t < 16; ++t) w2[t] = Wb[(slice * 16 + t) * HH + k];
  const float bias2 = bb[k];

  __syncthreads();

  float acc = 0.0f;
  int cur_i = -1;
  for (int t = 0; t < nedge; ++t) {
    const int i = si[t];
    const float4* hp = (const float4*)(sh1 + t * HH + slice * 16);
    float q = bias2;
#pragma unroll
    for (int u = 0; u < 4; ++u) {
      float4 h = hp[u];
      q = fmaf(h.x, w2[4 * u + 0], q);
      q = fmaf(h.y, w2[4 * u + 1], q);
      q = fmaf(h.z, w2[4 * u + 2], q);
      q = fmaf(h.w, w2[4 * u + 3], q);
    }
    q += __shfl_down(q, 32);
    q += __shfl_down(q, 16);
    const float h2 = fmaxf(q, 0.0f);
    if (i != cur_i) {
      if (cur_i >= 0 && lane < 16) atomicAdd(&xout[(cur_i << 6) + k], acc);
      acc = 0.0f;
      cur_i = i;
    }
    acc += h2;
  }
  if (cur_i >= 0 && lane < 16) atomicAdd(&xout[(cur_i << 6) + k], acc);
}

// x2[768,64] -> relu(x2 @ W3[64,128] + b3) -> sigmoid(@ W4[128,1] + b4)
__global__ __launch_bounds__(128) void final_kernel(
    const float* __restrict__ x2, const float* __restrict__ W3,
    const float* __restrict__ b3, const float* __restrict__ W4,
    const float* __restrict__ b4, float* __restrict__ out)
{
  const int i = blockIdx.x;
  const int t = threadIdx.x;
  const int lane = t & 63;
  const int wv = t >> 6;
  __shared__ float sx[64];
  __shared__ float s_red[2];
  if (t < 64) sx[t] = x2[i * 64 + t];
  __syncthreads();
  float p = b3[t];
#pragma unroll
  for (int c = 0; c < 64; ++c) p = fmaf(sx[c], W3[c * 128 + t], p);
  p = fmaxf(p, 0.0f);
  float v = p * W4[t];
  v += __shfl_down(v, 32);
  v += __shfl_down(v, 16);
  v += __shfl_down(v, 8);
  v += __shfl_down(v, 4);
  v += __shfl_down(v, 2);
  v += __shfl_down(v, 1);
  if (lane == 0) s_red[wv] = v;
  __syncthreads();
  if (t == 0) {
    float z = s_red[0] + s_red[1] + b4[0];
    out[i] = 1.0f / (1.0f + expf(-z));
  }
}

extern "C" void kernel_launch(void* const* d_in, const int* in_sizes, int n_in,
                              void* d_out, int out_size, void* d_ws, size_t ws_size,
                              hipStream_t stream) {
  const float* A   = (const float*)d_in[0];
  const float* x   = (const float*)d_in[1];
  const float* e   = (const float*)d_in[2];
  const float* W1a = (const float*)d_in[3];
  const float* b1a = (const float*)d_in[4];
  const float* W1b = (const float*)d_in[5];
  const float* b1b = (const float*)d_in[6];
  const float* W2a = (const float*)d_in[7];
  const float* b2a = (const float*)d_in[8];
  const float* W2b = (const float*)d_in[9];
  const float* b2b = (const float*)d_in[10];
  const float* W3  = (const float*)d_in[11];
  const float* b3  = (const float*)d_in[12];
  const float* W4  = (const float*)d_in[13];
  const float* b4  = (const float*)d_in[14];
  float* out = (float*)d_out;

  // ws layout: [gcnt(16 ints) | x1 | x2 | U1 | V1 | U2 | V2 | edges | ew2]
  int*   gcnt  = (int*)d_ws;
  float* x1    = (float*)d_ws + 16;
  float* x2    = x1 + NN * HH;
  float* U1    = x2 + NN * HH;
  float* V1    = U1 + NN * HH;
  float* U2    = V1 + NN * HH;
  float* V2    = U2 + NN * HH;
  int*   edges = (int*)(V2 + NN * HH);
  float* ew2   = (float*)(edges + ECAP);

  hipMemsetAsync(gcnt, 0, 16 * sizeof(int), stream);

  scan_uv_kernel<<<NN, 256, 0, stream>>>(A, x, W1a, b1a, gcnt, edges, U1, V1, x1, x2);
  conv1_kernel<<<CGRID, 256, 0, stream>>>(gcnt, edges, U1, V1, e,
                                          W1a + 128 * HH, W2a + 128 * HH,
                                          W1b, b1b, x1, ew2);
  uv_kernel<<<NN / 4, 256, 0, stream>>>(x1, W2a, b2a, U2, V2);
  conv2_kernel<<<CGRID, 256, 0, stream>>>(gcnt, edges, U2, V2, ew2, W2b, b2b, x2);
  final_kernel<<<NN, 128, 0, stream>>>(x2, W3, b3, W4, b4, out);
}

// Round 8
// 179.091 us; speedup vs baseline: 2.7388x; 1.0125x over previous
//
#include <hip/hip_runtime.h>
#include <math.h>

// Sparse EdgeConvE round 8: phase B (h1 @ Wb, 4096 MAC/edge = 97% of FLOPs)
// moved to bf16 MFMA (fp32 accumulate). Phase A stays fp32 VALU.
//   h1 = relu( U[i] + V[j] + e_ij @ We ),  U = x@(Wxi-Wxj)+ba, V = x@Wxj
//   out[i] = sum_j relu( h1 @ Wb + bb )
// Per conv block (32 edges): H1[32x64]bf16 in LDS (stride 72: 2-way banks),
// Wb pre-packed in B-fragment order (bf16, ws). Wave w -> row-tile w>>1,
// col-tiles {2(w&1), 2(w&1)+1}; 4 mfma_f32_16x16x32_bf16 per wave.
// C/D layout: col=lane&15, row=(lane>>4)*4+reg  [verified m89].

#define NN 768
#define FF 64
#define DE 32
#define HH 64
#define EPB 32
#define CGRID 1024
#define ECAP (NN * 128)
#define SH1S 72              // padded LDS stride (shorts) for h1 rows

using bf16x8 = __attribute__((ext_vector_type(8))) short;
using f32x4  = __attribute__((ext_vector_type(4))) float;

__device__ __forceinline__ short f2b(float f) {
  unsigned u = __float_as_uint(f);
  return (short)((u + 0x7fffu + ((u >> 16) & 1u)) >> 16);   // RNE
}

// row scan -> flat edge list; U1/V1; zero x1/x2; blocks 0/1 pack Wb1/Wb2
// into B-fragment order: idx L: j=L&7, n=(L>>3)&15, quad=(L>>7)&3,
// kb=(L>>9)&1, ct=L>>10;  Wbp[L] = bf16( Wb[(kb*32+quad*8+j)*64 + ct*16+n] )
__global__ __launch_bounds__(256) void scan_uv_kernel(
    const float* __restrict__ A, const float* __restrict__ x,
    const float* __restrict__ W, const float* __restrict__ bias,
    const float* __restrict__ Wb1, const float* __restrict__ Wb2,
    int* __restrict__ gcnt, int* __restrict__ edges,
    float* __restrict__ U, float* __restrict__ V,
    float* __restrict__ x1, float* __restrict__ x2,
    short* __restrict__ Wbp1, short* __restrict__ Wbp2)
{
  const int i = blockIdx.x;
  const int tid = threadIdx.x;
  __shared__ int s_cnt, s_base;
  __shared__ int s_j[NN];
  __shared__ float sx[64];
  __shared__ float su[4][64], sv[4][64];

  if (tid == 0) s_cnt = 0;
  __syncthreads();
  if (tid < 64) sx[tid] = x[i * 64 + tid];
  for (int j = tid; j < NN; j += 256) {
    if (A[i * NN + j] != 0.0f) {
      int p = atomicAdd(&s_cnt, 1);
      s_j[p] = j;
    }
  }
  if (tid < 64) { x1[i * 64 + tid] = 0.0f; x2[i * 64 + tid] = 0.0f; }

  if (i < 2) {   // fragment-pack Wb for the convs
    const float* src = (i == 0) ? Wb1 : Wb2;
    short* dst = (i == 0) ? Wbp1 : Wbp2;
    for (int L = tid; L < 4096; L += 256) {
      const int j = L & 7, n = (L >> 3) & 15, quad = (L >> 7) & 3;
      const int kb = (L >> 9) & 1, ct = L >> 10;
      dst[L] = f2b(src[(kb * 32 + quad * 8 + j) * 64 + ct * 16 + n]);
    }
  }
  __syncthreads();

  {
    const int c = tid & 63, qr = tid >> 6;
    float u = 0.0f, v = 0.0f;
#pragma unroll
    for (int t = 0; t < 16; ++t) {
      const int d = qr * 16 + t;
      const float xv = sx[d];
      const float wxi = W[d * 64 + c];
      const float wxj = W[(64 + d) * 64 + c];
      u = fmaf(xv, wxi - wxj, u);
      v = fmaf(xv, wxj, v);
    }
    su[qr][c] = u; sv[qr][c] = v;
  }
  if (tid == 0) s_base = atomicAdd(gcnt, s_cnt);
  __syncthreads();

  if (tid < 64) {
    U[i * 64 + tid] = su[0][tid] + su[1][tid] + su[2][tid] + su[3][tid] + bias[tid];
    V[i * 64 + tid] = sv[0][tid] + sv[1][tid] + sv[2][tid] + sv[3][tid];
  }
  const int c = s_cnt, b = s_base;
  for (int t = tid; t < c; t += 256) edges[b + t] = (i << 10) | s_j[t];
}

// U2/V2 from x1
__global__ __launch_bounds__(256, 4) void uv_kernel(
    const float* __restrict__ x, const float* __restrict__ W,
    const float* __restrict__ bias, float* __restrict__ U, float* __restrict__ V)
{
  const int tid = threadIdx.x;
  const int rr = tid >> 6, c = tid & 63;
  const int r = blockIdx.x * 4 + rr;
  __shared__ float sx[4][64];
  sx[rr][c] = x[r * 64 + c];
  __syncthreads();
  float u = bias[c], v = 0.0f;
#pragma unroll
  for (int d = 0; d < 64; ++d) {
    float xv = sx[rr][d];
    float wxi = W[d * 64 + c];
    float wxj = W[(64 + d) * 64 + c];
    u = fmaf(xv, wxi - wxj, u);
    v = fmaf(xv, wxj, v);
  }
  U[r * 64 + c] = u;
  V[r * 64 + c] = v;
}

// shared phase-B: MFMA h1@Wb + bias/relu + run-length atomic aggregate
__device__ __forceinline__ void phaseB_mfma(
    const short* __restrict__ sh1b, const int* __restrict__ si,
    const short* __restrict__ Wbp, const float* __restrict__ bb,
    float* __restrict__ xout, int lane, int wv, int nedge)
{
  const int q = lane >> 4, n = lane & 15;
  const int rt = wv >> 1;
  const int ctbase = (wv & 1) * 2;

  // B-fragments: 2 ct x 2 kb, each one coalesced 16B load
  bf16x8 bf00 = *(const bf16x8*)(Wbp + ((((ctbase + 0) * 2 + 0) * 4 + q) * 16 + n) * 8);
  bf16x8 bf01 = *(const bf16x8*)(Wbp + ((((ctbase + 0) * 2 + 1) * 4 + q) * 16 + n) * 8);
  bf16x8 bf10 = *(const bf16x8*)(Wbp + ((((ctbase + 1) * 2 + 0) * 4 + q) * 16 + n) * 8);
  bf16x8 bf11 = *(const bf16x8*)(Wbp + ((((ctbase + 1) * 2 + 1) * 4 + q) * 16 + n) * 8);
  const float bias0 = bb[(ctbase + 0) * 16 + n];
  const float bias1 = bb[(ctbase + 1) * 16 + n];

  // A-fragments: lane holds A[m=lane&15][k=quad*8+j]
  const short* sa = sh1b + (rt * 16 + n) * SH1S + q * 8;
  bf16x8 a0 = *(const bf16x8*)(sa);        // k 0..31
  bf16x8 a1 = *(const bf16x8*)(sa + 32);   // k 32..63

  f32x4 acc0 = {0.f, 0.f, 0.f, 0.f}, acc1 = {0.f, 0.f, 0.f, 0.f};
  acc0 = __builtin_amdgcn_mfma_f32_16x16x32_bf16(a0, bf00, acc0, 0, 0, 0);
  acc0 = __builtin_amdgcn_mfma_f32_16x16x32_bf16(a1, bf01, acc0, 0, 0, 0);
  acc1 = __builtin_amdgcn_mfma_f32_16x16x32_bf16(a0, bf10, acc1, 0, 0, 0);
  acc1 = __builtin_amdgcn_mfma_f32_16x16x32_bf16(a1, bf11, acc1, 0, 0, 0);

#pragma unroll
  for (int c2 = 0; c2 < 2; ++c2) {
    const f32x4 d = c2 ? acc1 : acc0;
    const float bias = c2 ? bias1 : bias0;
    const int ch = (ctbase + c2) * 16 + n;
    float sum = 0.0f;
    int cur = -1;
#pragma unroll
    for (int reg = 0; reg < 4; ++reg) {
      const int t = rt * 16 + q * 4 + reg;   // edge slot (C/D row)
      if (t < nedge) {
        const int it = si[t];
        const float v = fmaxf(d[reg] + bias, 0.0f);
        if (it != cur) {
          if (cur >= 0) atomicAdd(&xout[(cur << 6) + ch], sum);
          sum = 0.0f;
          cur = it;
        }
        sum += v;
      }
    }
    if (cur >= 0) atomicAdd(&xout[(cur << 6) + ch], sum);
  }
}

// conv layer 1 (+ ew2 = e @ We2 side product)
__global__ void conv1_kernel(
    const int* __restrict__ gcnt, const int* __restrict__ edges,
    const float* __restrict__ U, const float* __restrict__ V,
    const float* __restrict__ e, const float* __restrict__ We1,
    const float* __restrict__ We2, const short* __restrict__ Wbp,
    const float* __restrict__ bb, float* __restrict__ xout,
    float* __restrict__ ew2)
{
  const int tid = threadIdx.x, lane = tid & 63, wv = tid >> 6;
  const int M = gcnt[0];
  const int base = blockIdx.x * EPB;
  if (base >= M) return;
  const int nedge = min(EPB, M - base);

  __shared__ __align__(16) short sh1b[EPB * SH1S];
  __shared__ int si[EPB];

  float w1e[DE], w2e[DE];
#pragma unroll
  for (int d = 0; d < DE; ++d) { w1e[d] = We1[d * HH + lane]; w2e[d] = We2[d * HH + lane]; }

  const int a0 = wv * 8;
#pragma unroll
  for (int t = 0; t < 8; ++t) {
    int m = base + a0 + t;
    const bool valid = m < M;
    m = valid ? m : M - 1;
    const int p = edges[m];
    const int i = p >> 10, j = p & 1023;
    float h = U[(i << 6) + lane] + V[(j << 6) + lane];
    float g = 0.0f;
    const float4* ep = (const float4*)(e + ((size_t)i * NN + j) * DE);
#pragma unroll
    for (int u = 0; u < 8; ++u) {
      float4 f = ep[u];
      h = fmaf(f.x, w1e[4 * u + 0], h);
      h = fmaf(f.y, w1e[4 * u + 1], h);
      h = fmaf(f.z, w1e[4 * u + 2], h);
      h = fmaf(f.w, w1e[4 * u + 3], h);
      g = fmaf(f.x, w2e[4 * u + 0], g);
      g = fmaf(f.y, w2e[4 * u + 1], g);
      g = fmaf(f.z, w2e[4 * u + 2], g);
      g = fmaf(f.w, w2e[4 * u + 3], g);
    }
    sh1b[(a0 + t) * SH1S + lane] = f2b(fmaxf(h, 0.0f));
    if (valid) ew2[(size_t)m * HH + lane] = g;
    if (lane == 0) si[a0 + t] = i;
  }
  __syncthreads();

  phaseB_mfma(sh1b, si, Wbp, bb, xout, lane, wv, nedge);
}

// conv layer 2: e-part precomputed (sequential ew2 rows)
__global__ void conv2_kernel(
    const int* __restrict__ gcnt, const int* __restrict__ edges,
    const float* __restrict__ U, const float* __restrict__ V,
    const float* __restrict__ ew2, const short* __restrict__ Wbp,
    const float* __restrict__ bb, float* __restrict__ xout)
{
  const int tid = threadIdx.x, lane = tid & 63, wv = tid >> 6;
  const int M = gcnt[0];
  const int base = blockIdx.x * EPB;
  if (base >= M) return;
  const int nedge = min(EPB, M - base);

  __shared__ __align__(16) short sh1b[EPB * SH1S];
  __shared__ int si[EPB];

  const int a0 = wv * 8;
#pragma unroll
  for (int t = 0; t < 8; ++t) {
    int m = base + a0 + t;
    m = m < M ? m : M - 1;
    const int p = edges[m];
    const int i = p >> 10, j = p & 1023;
    const float h = U[(i << 6) + lane] + V[(j << 6) + lane]
                  + ew2[(size_t)m * HH + lane];
    sh1b[(a0 + t) * SH1S + lane] = f2b(fmaxf(h, 0.0f));
    if (lane == 0) si[a0 + t] = i;
  }
  __syncthreads();

  phaseB_mfma(sh1b, si, Wbp, bb, xout, lane, wv, nedge);
}

// x2[768,64] -> relu(x2 @ W3[64,128] + b3) -> sigmoid(@ W4[128,1] + b4)
__global__ __launch_bounds__(128) void final_kernel(
    const float* __restrict__ x2, const float* __restrict__ W3,
    const float* __restrict__ b3, const float* __restrict__ W4,
    const float* __restrict__ b4, float* __restrict__ out)
{
  const int i = blockIdx.x;
  const int t = threadIdx.x;
  const int lane = t & 63;
  const int wv = t >> 6;
  __shared__ float sx[64];
  __shared__ float s_red[2];
  if (t < 64) sx[t] = x2[i * 64 + t];
  __syncthreads();
  float p = b3[t];
#pragma unroll
  for (int c = 0; c < 64; ++c) p = fmaf(sx[c], W3[c * 128 + t], p);
  p = fmaxf(p, 0.0f);
  float v = p * W4[t];
  v += __shfl_down(v, 32);
  v += __shfl_down(v, 16);
  v += __shfl_down(v, 8);
  v += __shfl_down(v, 4);
  v += __shfl_down(v, 2);
  v += __shfl_down(v, 1);
  if (lane == 0) s_red[wv] = v;
  __syncthreads();
  if (t == 0) {
    float z = s_red[0] + s_red[1] + b4[0];
    out[i] = 1.0f / (1.0f + expf(-z));
  }
}

extern "C" void kernel_launch(void* const* d_in, const int* in_sizes, int n_in,
                              void* d_out, int out_size, void* d_ws, size_t ws_size,
                              hipStream_t stream) {
  const float* A   = (const float*)d_in[0];
  const float* x   = (const float*)d_in[1];
  const float* e   = (const float*)d_in[2];
  const float* W1a = (const float*)d_in[3];
  const float* b1a = (const float*)d_in[4];
  const float* W1b = (const float*)d_in[5];
  const float* b1b = (const float*)d_in[6];
  const float* W2a = (const float*)d_in[7];
  const float* b2a = (const float*)d_in[8];
  const float* W2b = (const float*)d_in[9];
  const float* b2b = (const float*)d_in[10];
  const float* W3  = (const float*)d_in[11];
  const float* b3  = (const float*)d_in[12];
  const float* W4  = (const float*)d_in[13];
  const float* b4  = (const float*)d_in[14];
  float* out = (float*)d_out;

  // ws: [gcnt(16i) | x1 | x2 | U1 | V1 | U2 | V2 | edges | ew2 | Wbp1 | Wbp2]
  int*   gcnt  = (int*)d_ws;
  float* x1    = (float*)d_ws + 16;
  float* x2    = x1 + NN * HH;
  float* U1    = x2 + NN * HH;
  float* V1    = U1 + NN * HH;
  float* U2    = V1 + NN * HH;
  float* V2    = U2 + NN * HH;
  int*   edges = (int*)(V2 + NN * HH);
  float* ew2   = (float*)(edges + ECAP);
  short* Wbp1  = (short*)(ew2 + (size_t)CGRID * EPB * HH);
  short* Wbp2  = Wbp1 + 4096;

  hipMemsetAsync(gcnt, 0, 16 * sizeof(int), stream);

  scan_uv_kernel<<<NN, 256, 0, stream>>>(A, x, W1a, b1a, W1b, W2b,
                                         gcnt, edges, U1, V1, x1, x2, Wbp1, Wbp2);
  conv1_kernel<<<CGRID, 256, 0, stream>>>(gcnt, edges, U1, V1, e,
                                          W1a + 128 * HH, W2a + 128 * HH,
                                          Wbp1, b1b, x1, ew2);
  uv_kernel<<<NN / 4, 256, 0, stream>>>(x1, W2a, b2a, U2, V2);
  conv2_kernel<<<CGRID, 256, 0, stream>>>(gcnt, edges, U2, V2, ew2,
                                          Wbp2, b2b, x2);
  final_kernel<<<NN, 128, 0, stream>>>(x2, W3, b3, W4, b4, out);
}